// Round 1
// 2065.600 us; speedup vs baseline: 1.0853x; 1.0853x over previous
//
#include <hip/hip_runtime.h>

typedef unsigned short u16;
typedef short bf16x8 __attribute__((ext_vector_type(8)));
typedef float f32x4 __attribute__((ext_vector_type(4)));

#define SCALE_F 0.08838834764831845f

// VEC offsets (u16 elems)
#define VC_PW    0
#define VC_PB    1408
#define VC_N1W   1536
#define VC_N1B   1792
#define VC_QKVB  2048
#define VC_PROJB 2816
#define VC_N2W   3072
#define VC_N2B   3328
#define VC_B1    3584
#define VC_B2    4608
#define VC_NFW   4864
#define VC_NFB   4992
#define VC_RPB   5120
#define VC_OW    6592
#define VC_OBIAS 44480

// WT offsets (u16 elems) — transposed weights [N][K]
#define WT_QKV  0
#define WT_PROJ 98304
#define WT_W1   131072
#define WT_W2   262144

__device__ __forceinline__ float bf2f(u16 x) {
  union { unsigned int i; float f; } v; v.i = ((unsigned int)x) << 16; return v.f;
}
__device__ __forceinline__ u16 f2bf(float f) {
  union { float f; unsigned int i; } v; v.f = f;
  unsigned int x = v.i;
  return (u16)((x + 0x7fffu + ((x >> 16) & 1u)) >> 16);
}
__device__ __forceinline__ unsigned int packbf(float a, float b) {
  return (unsigned int)f2bf(a) | ((unsigned int)f2bf(b) << 16);
}
__device__ __forceinline__ float wsum(float v) {
#pragma unroll
  for (int m = 32; m >= 1; m >>= 1) v += __shfl_xor(v, m, 64);
  return v;
}
__device__ __forceinline__ float gelu_f(float x) {
  float u = -1.5957691216057308f * x * (1.f + 0.044715f * x * x);
  float e = __expf(u);
  return x * __builtin_amdgcn_rcpf(1.f + e);
}

// -------- dtype scan + decide --------
__global__ __launch_bounds__(256) void k_scan(const u16* __restrict__ raw, int* __restrict__ flag) {
  int nanc = 0, ez = 0;
  for (int i = threadIdx.x; i < 131072; i += 256) {
    u16 x = raw[i];
    if ((x & 0x7F80u) == 0x7F80u) nanc++;
    if (!(i & 1) && x == 0) ez++;
  }
  atomicAdd(&flag[1], nanc);
  atomicAdd(&flag[2], ez);
}
__global__ void k_decide(int* __restrict__ flag) {
  if (threadIdx.x == 0) flag[0] = (flag[1] > 0 || flag[2] > 49152) ? 1 : 0;
}

// -------- dual-mode converts --------
__global__ __launch_bounds__(256) void k_conv(const void* __restrict__ src, u16* __restrict__ dst,
                                              int n, const int* __restrict__ flag) {
  const int fl = *flag;
  int i = blockIdx.x * 256 + threadIdx.x;
  if (i < n) dst[i] = fl ? f2bf(((const float*)src)[i]) : ((const u16*)src)[i];
}
__global__ __launch_bounds__(256) void k_convT2(const void* __restrict__ src, u16* __restrict__ dst,
                                                int K, int N, int eoff, const int* __restrict__ flag) {
  const int fl = *flag;
  int id = blockIdx.x * 256 + threadIdx.x;
  if (id < K * N) {
    int n = id / K, k = id % K;
    dst[id] = fl ? f2bf(((const float*)src)[eoff + k * N + n])
                 : ((const u16*)src)[eoff + k * N + n];
  }
}

// ---------------- patch embed ----------------
__global__ __launch_bounds__(256) void k_patch(const u16* __restrict__ obs,
                                               const u16* __restrict__ vec,
                                               u16* __restrict__ X) {
  __shared__ float vis[11][40];
  __shared__ float spw[11][128];
  __shared__ float spb[128];
  const int tid = threadIdx.x;
  const int bdh = blockIdx.x;
  const int b = bdh / 300, rem = bdh % 300;
  const int d = rem / 30, h = rem % 30;
  for (int i = tid; i < 1408; i += 256) spw[i >> 7][i & 127] = bf2f(vec[VC_PW + i]);
  if (tid < 128) spb[tid] = bf2f(vec[VC_PB + tid]);
  for (int i = tid; i < 440; i += 256) {
    int ch = i / 40, w = i % 40;
    vis[ch][w] = bf2f(obs[(size_t)b * 132020 + ((d * 11 + ch) * 30 + h) * 40 + w]);
  }
  __syncthreads();
  const size_t xbase = ((size_t)b * 12000 + d * 1200 + h * 40) * 128;
  for (int o = tid; o < 40 * 128; o += 256) {
    int w = o >> 7, c = o & 127;
    float acc = spb[c];
#pragma unroll
    for (int ch = 0; ch < 11; ch++) acc += vis[ch][w] * spw[ch][c];
    X[xbase + o] = f2bf(acc);
  }
}

// ================== fused per-window: LN1 + QKV + attention + proj + residual ==================
// One block per window (3072), 512 threads (8 waves), 64 KB LDS -> 2 blocks/CU.
// BufA: Y (wave-private, transient) -> K (cross-wave) -> V^T (cross-wave).
// BufB: Q -> P -> O (all wave-private rows).
// V is held in 16 packed VGPRs between its MFMA (pre-barrier-1) and the V^T
// scatter (post-barrier-2), which is what lets K's region be reused for V^T.
__global__ __launch_bounds__(512, 4) void k_win(u16* __restrict__ X,
                                                const u16* __restrict__ Wqkv,   // [384][128]
                                                const u16* __restrict__ Wproj,  // [128][128]
                                                const u16* __restrict__ qkvb,
                                                const u16* __restrict__ projb,
                                                const u16* __restrict__ nw, const u16* __restrict__ nb,
                                                const u16* __restrict__ rpb,
                                                int shift, int boundary) {
  __shared__ u16 sA[128 * 128];   // Y -> K -> V^T
  __shared__ u16 sB[128 * 128];   // Q -> P -> O
  const int tid = threadIdx.x, lane = tid & 63, wv = tid >> 6;
  const int m16 = lane & 15, quad = lane >> 4;
  const int wing = blockIdx.x;
  const int b = wing / 96, winb = wing % 96;
  const int wd = winb / 48, wh = (winb >> 3) % 6, ww = winb & 7;
  const int tok = wv * 16 + m16;          // lane's token (0..127)
  const int tokc = tok > 124 ? 124 : tok;

  // ---- LN + roll + gather: wave handles its own 16 rows (into sA) ----
  const float nw0 = bf2f(nw[2 * lane]), nb0 = bf2f(nb[2 * lane]);
  const float nw1 = bf2f(nw[2 * lane + 1]), nb1 = bf2f(nb[2 * lane + 1]);
  for (int r = 0; r < 16; r++) {
    int row = wv * 16 + r;
    int n = row > 124 ? 124 : row;
    int ld = n / 25, lh = (n / 5) % 5, lw = n % 5;
    int d = wd * 5 + ld + shift; if (d >= 10) d -= 10;
    int h = wh * 5 + lh + shift; if (h >= 30) h -= 30;
    int w2 = ww * 5 + lw + shift; if (w2 >= 40) w2 -= 40;
    const u16* xp = X + ((((size_t)b * 10 + d) * 30 + h) * 40 + w2) * 128;
    unsigned int u = *(const unsigned int*)(xp + 2 * lane);
    float x0 = bf2f((u16)(u & 0xffff)), x1 = bf2f((u16)(u >> 16));
    float mean = wsum(x0 + x1) * (1.f / 128.f);
    float var = wsum(x0 * x0 + x1 * x1) * (1.f / 128.f) - mean * mean;
    float rstd = rsqrtf(var + 1e-5f);
    float y0 = (x0 - mean) * rstd * nw0 + nb0;
    float y1 = (x1 - mean) * rstd * nw1 + nb1;
    *(unsigned int*)(sA + row * 128 + (((lane >> 2) ^ (row & 15)) << 3) + ((2 * lane) & 7)) =
        packbf(y0, y1);
  }
  // B-fragments of this wave's own token rows (no barrier: own-row write->read, lockstep)
  bf16x8 biY[4];
#pragma unroll
  for (int kc = 0; kc < 4; kc++)
    biY[kc] = *(const bf16x8*)(sA + tok * 128 + (((4 * kc + quad) ^ m16) << 3));

  // ---- K -> sA[tok][ch] (overwrites Y; own-row, lockstep-safe after biY reads) ----
#pragma unroll
  for (int mt = 0; mt < 8; mt++) {
    f32x4 acc; acc[0] = 0.f; acc[1] = 0.f; acc[2] = 0.f; acc[3] = 0.f;
#pragma unroll
    for (int kc = 0; kc < 4; kc++) {
      bf16x8 a = *(const bf16x8*)(Wqkv + (size_t)(128 + mt * 16 + m16) * 128 + kc * 32 + quad * 8);
      acc = __builtin_amdgcn_mfma_f32_16x16x32_bf16(a, biY[kc], acc, 0, 0, 0);
    }
    int oc = mt * 16 + quad * 4;
    uint2 pk;
    pk.x = packbf(acc[0] + bf2f(qkvb[128 + oc]), acc[1] + bf2f(qkvb[128 + oc + 1]));
    pk.y = packbf(acc[2] + bf2f(qkvb[128 + oc + 2]), acc[3] + bf2f(qkvb[128 + oc + 3]));
    *(uint2*)(sA + tok * 128 + (((2 * mt + (quad >> 1)) ^ m16) << 3) + ((quad & 1) << 2)) = pk;
  }
  // ---- Q (scaled) -> sB[tok][ch] (wave-private) ----
#pragma unroll
  for (int mt = 0; mt < 8; mt++) {
    f32x4 acc; acc[0] = 0.f; acc[1] = 0.f; acc[2] = 0.f; acc[3] = 0.f;
#pragma unroll
    for (int kc = 0; kc < 4; kc++) {
      bf16x8 a = *(const bf16x8*)(Wqkv + (size_t)(mt * 16 + m16) * 128 + kc * 32 + quad * 8);
      acc = __builtin_amdgcn_mfma_f32_16x16x32_bf16(a, biY[kc], acc, 0, 0, 0);
    }
    int oc = mt * 16 + quad * 4;
    uint2 pk;
    pk.x = packbf((acc[0] + bf2f(qkvb[oc])) * SCALE_F, (acc[1] + bf2f(qkvb[oc + 1])) * SCALE_F);
    pk.y = packbf((acc[2] + bf2f(qkvb[oc + 2])) * SCALE_F, (acc[3] + bf2f(qkvb[oc + 3])) * SCALE_F);
    *(uint2*)(sB + tok * 128 + (((2 * mt + (quad >> 1)) ^ m16) << 3) + ((quad & 1) << 2)) = pk;
  }
  // ---- V -> registers (packed bf16, deferred V^T scatter) ----
  uint2 vreg[8];
#pragma unroll
  for (int mt = 0; mt < 8; mt++) {
    f32x4 acc; acc[0] = 0.f; acc[1] = 0.f; acc[2] = 0.f; acc[3] = 0.f;
#pragma unroll
    for (int kc = 0; kc < 4; kc++) {
      bf16x8 a = *(const bf16x8*)(Wqkv + (size_t)(256 + mt * 16 + m16) * 128 + kc * 32 + quad * 8);
      acc = __builtin_amdgcn_mfma_f32_16x16x32_bf16(a, biY[kc], acc, 0, 0, 0);
    }
    int oc = mt * 16 + quad * 4;
    vreg[mt].x = packbf(acc[0] + bf2f(qkvb[256 + oc]), acc[1] + bf2f(qkvb[256 + oc + 1]));
    vreg[mt].y = packbf(acc[2] + bf2f(qkvb[256 + oc + 2]), acc[3] + bf2f(qkvb[256 + oc + 3]));
  }
  __syncthreads();  // barrier 1: K visible to all waves

  // ---- S^T = K·Q^T : A = sA rows (j), B = own Q rows from sB ----
  f32x4 S[8];
#pragma unroll
  for (int jt = 0; jt < 8; jt++) { S[jt][0] = 0.f; S[jt][1] = 0.f; S[jt][2] = 0.f; S[jt][3] = 0.f; }
#pragma unroll
  for (int kc = 0; kc < 4; kc++) {
    bf16x8 qf = *(const bf16x8*)(sB + tok * 128 + (((4 * kc + quad) ^ m16) << 3));
#pragma unroll
    for (int jt = 0; jt < 8; jt++) {
      int row = jt * 16 + m16;
      bf16x8 kf = *(const bf16x8*)(sA + row * 128 + (((4 * kc + quad) ^ m16) << 3));
      S[jt] = __builtin_amdgcn_mfma_f32_16x16x32_bf16(kf, qf, S[jt], 0, 0, 0);
    }
  }
  // ---- bias + masks + softmax (lane owns q=tok column; j = jt*16+quad*4+r) ----
  const int ldq = tokc / 25, lhq = (tokc / 5) % 5, lwq = tokc % 5;
  int regQ = 0;
  if (boundary) {
    int gd = wd * 5 + ldq, gh = wh * 5 + lhq, gw = ww * 5 + lwq;
    regQ = (gd < 5 ? 0 : (gd < 8 ? 1 : 2)) * 9 + (gh < 25 ? 0 : (gh < 28 ? 1 : 2)) * 3 +
           (gw < 35 ? 0 : (gw < 38 ? 1 : 2));
  }
  float mx = -1e30f;
#pragma unroll
  for (int jt = 0; jt < 8; jt++) {
#pragma unroll
    for (int r = 0; r < 4; r++) {
      int j = jt * 16 + quad * 4 + r;
      bool jvalid = j < 125;
      int jc = jvalid ? j : 124;
      int ldk = jc / 25, lhk = (jc / 5) % 5, lwk = jc % 5;
      float s = S[jt][r];
      int idx = ((ldq - ldk + 4) * 9 + (lhq - lhk + 4)) * 9 + (lwq - lwk + 4);
      s += bf2f(rpb[idx]);
      if (ldq < ldk) s -= 100.f;
      if (boundary) {
        int gd = wd * 5 + ldk, gh = wh * 5 + lhk, gw = ww * 5 + lwk;
        int regK = (gd < 5 ? 0 : (gd < 8 ? 1 : 2)) * 9 + (gh < 25 ? 0 : (gh < 28 ? 1 : 2)) * 3 +
                   (gw < 35 ? 0 : (gw < 38 ? 1 : 2));
        if (regQ != regK) s -= 100.f;
      }
      if (!jvalid) s = -1e30f;
      S[jt][r] = s;
      mx = fmaxf(mx, s);
    }
  }
  mx = fmaxf(mx, __shfl_xor(mx, 16, 64));
  mx = fmaxf(mx, __shfl_xor(mx, 32, 64));
  float sm = 0.f;
#pragma unroll
  for (int jt = 0; jt < 8; jt++)
#pragma unroll
    for (int r = 0; r < 4; r++) {
      float e = __expf(S[jt][r] - mx);
      S[jt][r] = e;
      sm += e;
    }
  sm += __shfl_xor(sm, 16, 64);
  sm += __shfl_xor(sm, 32, 64);
  float inv = 1.f / sm;
  // P -> sB own rows (overwrites Q; own-wave only, lockstep-safe)
#pragma unroll
  for (int jt = 0; jt < 8; jt++) {
    uint2 pk;
    pk.x = packbf(S[jt][0] * inv, S[jt][1] * inv);
    pk.y = packbf(S[jt][2] * inv, S[jt][3] * inv);
    *(uint2*)(sB + tok * 128 + (((2 * jt + (quad >> 1)) ^ m16) << 3) + ((quad & 1) << 2)) = pk;
  }
  __syncthreads();  // barrier 2: all waves done reading sA (K)
  // ---- deferred V^T scatter into sA (overwrites K) ----
#pragma unroll
  for (int mt = 0; mt < 8; mt++) {
    int c0 = mt * 16 + quad * 4;
    sA[(c0 + 0) * 128 + ((((tok >> 3) ^ ((c0 + 0) & 15))) << 3) + (tok & 7)] = (u16)(vreg[mt].x & 0xffffu);
    sA[(c0 + 1) * 128 + ((((tok >> 3) ^ ((c0 + 1) & 15))) << 3) + (tok & 7)] = (u16)(vreg[mt].x >> 16);
    sA[(c0 + 2) * 128 + ((((tok >> 3) ^ ((c0 + 2) & 15))) << 3) + (tok & 7)] = (u16)(vreg[mt].y & 0xffffu);
    sA[(c0 + 3) * 128 + ((((tok >> 3) ^ ((c0 + 3) & 15))) << 3) + (tok & 7)] = (u16)(vreg[mt].y >> 16);
  }
  __syncthreads();  // barrier 3: V^T visible to all waves
  // ---- O^T = VT·P : A = sA rows (c), B = own P rows from sB ----
  f32x4 O[8];
#pragma unroll
  for (int ct = 0; ct < 8; ct++) { O[ct][0] = 0.f; O[ct][1] = 0.f; O[ct][2] = 0.f; O[ct][3] = 0.f; }
#pragma unroll
  for (int kc = 0; kc < 4; kc++) {
    bf16x8 pf = *(const bf16x8*)(sB + tok * 128 + (((4 * kc + quad) ^ m16) << 3));
#pragma unroll
    for (int ct = 0; ct < 8; ct++) {
      int c = ct * 16 + m16;
      bf16x8 vf = *(const bf16x8*)(sA + c * 128 + (((4 * kc + quad) ^ m16) << 3));
      O[ct] = __builtin_amdgcn_mfma_f32_16x16x32_bf16(vf, pf, O[ct], 0, 0, 0);
    }
  }
  // O -> sB own rows as sO[tok][c] (overwrites P; own-wave only, lockstep-safe)
#pragma unroll
  for (int ct = 0; ct < 8; ct++) {
    uint2 pk;
    pk.x = packbf(O[ct][0], O[ct][1]);
    pk.y = packbf(O[ct][2], O[ct][3]);
    *(uint2*)(sB + tok * 128 + (((2 * ct + (quad >> 1)) ^ m16) << 3) + ((quad & 1) << 2)) = pk;
  }
  // proj B-frags (own rows)
  bf16x8 biO[4];
#pragma unroll
  for (int kc = 0; kc < 4; kc++)
    biO[kc] = *(const bf16x8*)(sB + tok * 128 + (((4 * kc + quad) ^ m16) << 3));
  // lane's scatter destination (roll-back)
  size_t xbase;
  {
    int ld = tokc / 25, lh = (tokc / 5) % 5, lw = tokc % 5;
    int d = wd * 5 + ld + shift; if (d >= 10) d -= 10;
    int h = wh * 5 + lh + shift; if (h >= 30) h -= 30;
    int w2 = ww * 5 + lw + shift; if (w2 >= 40) w2 -= 40;
    xbase = ((((size_t)b * 10 + d) * 30 + h) * 40 + w2) * 128;
  }
  // ---- proj^T = WpT·O^T + residual scatter-add ----
#pragma unroll
  for (int mt = 0; mt < 8; mt++) {
    f32x4 acc; acc[0] = 0.f; acc[1] = 0.f; acc[2] = 0.f; acc[3] = 0.f;
#pragma unroll
    for (int kc = 0; kc < 4; kc++) {
      bf16x8 a = *(const bf16x8*)(Wproj + (size_t)(mt * 16 + m16) * 128 + kc * 32 + quad * 8);
      acc = __builtin_amdgcn_mfma_f32_16x16x32_bf16(a, biO[kc], acc, 0, 0, 0);
    }
    if (tok < 125) {
      int oc = mt * 16 + quad * 4;
      u16* xp = X + xbase + oc;
      uint2 old = *(uint2*)xp;
      float f0 = bf2f((u16)(old.x & 0xffff)) + acc[0] + bf2f(projb[oc]);
      float f1 = bf2f((u16)(old.x >> 16)) + acc[1] + bf2f(projb[oc + 1]);
      float f2 = bf2f((u16)(old.y & 0xffff)) + acc[2] + bf2f(projb[oc + 2]);
      float f3 = bf2f((u16)(old.y >> 16)) + acc[3] + bf2f(projb[oc + 3]);
      uint2 nv;
      nv.x = packbf(f0, f1);
      nv.y = packbf(f2, f3);
      *(uint2*)xp = nv;
    }
  }
}

// ---------------- k_mlp v2 (unchanged from R11) ----------------
__global__ __launch_bounds__(512) void k_mlp(u16* __restrict__ X, const u16* __restrict__ W1T,
                                             const u16* __restrict__ b1, const u16* __restrict__ W2T,
                                             const u16* __restrict__ b2, const u16* __restrict__ nw,
                                             const u16* __restrict__ nb) {
  __shared__ u16 sIn[256 * 128];
  __shared__ u16 sW1[64 * 128];
  __shared__ u16 sH[256 * 64];
  __shared__ u16 sW2[128 * 64];
  const int tid = threadIdx.x, lane = tid & 63, wv = tid >> 6;
  const int m16 = lane & 15, quad = lane >> 4;
  const int mbase = blockIdx.x * 256;
  const float nw0 = bf2f(nw[2 * lane]), nb0 = bf2f(nb[2 * lane]);
  const float nw1 = bf2f(nw[2 * lane + 1]), nb1 = bf2f(nb[2 * lane + 1]);
  for (int r = 0; r < 32; r++) {
    int row = wv * 32 + r;
    unsigned int u = *(const unsigned int*)(X + (size_t)(mbase + row) * 128 + 2 * lane);
    float x0 = bf2f((u16)(u & 0xffff)), x1 = bf2f((u16)(u >> 16));
    float mean = wsum(x0 + x1) * (1.f / 128.f);
    float var = wsum(x0 * x0 + x1 * x1) * (1.f / 128.f) - mean * mean;
    float rstd = rsqrtf(var + 1e-5f);
    float y0 = (x0 - mean) * rstd * nw0 + nb0;
    float y1 = (x1 - mean) * rstd * nw1 + nb1;
    *(unsigned int*)(sIn + row * 128 + (((lane >> 2) ^ (row & 15)) << 3) + ((2 * lane) & 7)) =
        packbf(y0, y1);
  }
  f32x4 acc2[8][2];
#pragma unroll
  for (int mt = 0; mt < 8; mt++)
#pragma unroll
    for (int t = 0; t < 2; t++)
#pragma unroll
      for (int r = 0; r < 4; r++) acc2[mt][t][r] = 0.f;
  __syncthreads();
  for (int hc = 0; hc < 8; hc++) {
    for (int idx = tid; idx < 1024; idx += 512) {
      int row = idx >> 4, g = idx & 15;
      uint4 v = *(const uint4*)(W1T + (size_t)(hc * 64 + row) * 128 + g * 8);
      *(uint4*)(sW1 + row * 128 + ((g ^ (row & 15)) << 3)) = v;
    }
    for (int idx = tid; idx < 1024; idx += 512) {
      int row = idx >> 3, g = idx & 7;
      uint4 v = *(const uint4*)(W2T + (size_t)row * 512 + hc * 64 + g * 8);
      *(uint4*)(sW2 + row * 64 + ((g ^ (row & 7)) << 3)) = v;
    }
    __syncthreads();
    f32x4 h4[4][2];
#pragma unroll
    for (int nt = 0; nt < 4; nt++)
#pragma unroll
      for (int t = 0; t < 2; t++)
#pragma unroll
        for (int r = 0; r < 4; r++) h4[nt][t][r] = 0.f;
#pragma unroll
    for (int kc = 0; kc < 4; kc++) {
      bf16x8 bi[2];
#pragma unroll
      for (int t = 0; t < 2; t++) {
        int row = wv * 32 + t * 16 + m16;
        bi[t] = *(const bf16x8*)(sIn + row * 128 + (((4 * kc + quad) ^ m16) << 3));
      }
#pragma unroll
      for (int nt = 0; nt < 4; nt++) {
        int hrow = nt * 16 + m16;
        bf16x8 af = *(const bf16x8*)(sW1 + hrow * 128 + (((4 * kc + quad) ^ m16) << 3));
#pragma unroll
        for (int t = 0; t < 2; t++)
          h4[nt][t] = __builtin_amdgcn_mfma_f32_16x16x32_bf16(af, bi[t], h4[nt][t], 0, 0, 0);
      }
    }
    __syncthreads();
#pragma unroll
    for (int nt = 0; nt < 4; nt++) {
      int hb = nt * 16 + quad * 4;
      float bv0 = bf2f(b1[hc * 64 + hb]);
      float bv1 = bf2f(b1[hc * 64 + hb + 1]);
      float bv2 = bf2f(b1[hc * 64 + hb + 2]);
      float bv3 = bf2f(b1[hc * 64 + hb + 3]);
#pragma unroll
      for (int t = 0; t < 2; t++) {
        int tok = wv * 32 + t * 16 + m16;
        float g0 = gelu_f(h4[nt][t][0] + bv0);
        float g1 = gelu_f(h4[nt][t][1] + bv1);
        float g2 = gelu_f(h4[nt][t][2] + bv2);
        float g3 = gelu_f(h4[nt][t][3] + bv3);
        uint2 pk;
        pk.x = packbf(g0, g1);
        pk.y = packbf(g2, g3);
        int g16 = (2 * nt + (quad >> 1)) ^ (tok & 7);
        *(uint2*)(sH + tok * 64 + (g16 << 3) + ((quad & 1) << 2)) = pk;
      }
    }
    __syncthreads();
#pragma unroll
    for (int kc = 0; kc < 2; kc++) {
      bf16x8 bh[2];
#pragma unroll
      for (int t = 0; t < 2; t++) {
        int tok = wv * 32 + t * 16 + m16;
        bh[t] = *(const bf16x8*)(sH + tok * 64 + ((((4 * kc + quad) ^ (tok & 7))) << 3));
      }
#pragma unroll
      for (int mt = 0; mt < 8; mt++) {
        int oc = mt * 16 + m16;
        bf16x8 af = *(const bf16x8*)(sW2 + oc * 64 + ((((4 * kc + quad) ^ (oc & 7))) << 3));
#pragma unroll
        for (int t = 0; t < 2; t++)
          acc2[mt][t] = __builtin_amdgcn_mfma_f32_16x16x32_bf16(af, bh[t], acc2[mt][t], 0, 0, 0);
      }
    }
    __syncthreads();
  }
#pragma unroll
  for (int mt = 0; mt < 8; mt++) {
    int oc0 = mt * 16 + quad * 4;
    float bv0 = bf2f(b2[oc0]), bv1 = bf2f(b2[oc0 + 1]);
    float bv2 = bf2f(b2[oc0 + 2]), bv3 = bf2f(b2[oc0 + 3]);
#pragma unroll
    for (int t = 0; t < 2; t++) {
      int token = mbase + wv * 32 + t * 16 + m16;
      u16* xp = X + (size_t)token * 128 + oc0;
      uint2 old = *(uint2*)xp;
      float f0 = bf2f((u16)(old.x & 0xffff)) + acc2[mt][t][0] + bv0;
      float f1 = bf2f((u16)(old.x >> 16)) + acc2[mt][t][1] + bv1;
      float f2 = bf2f((u16)(old.y & 0xffff)) + acc2[mt][t][2] + bv2;
      float f3 = bf2f((u16)(old.y >> 16)) + acc2[mt][t][3] + bv3;
      uint2 nv;
      nv.x = packbf(f0, f1);
      nv.y = packbf(f2, f3);
      *(uint2*)xp = nv;
    }
  }
}

// ---------------- final LN + partial pooling ----------------
__global__ __launch_bounds__(256) void k_pool(const u16* __restrict__ X, const u16* __restrict__ vec,
                                              float* __restrict__ pool) {
  __shared__ float sacc[4][128];
  const int tid = threadIdx.x, lane = tid & 63, wv = tid >> 6;
  const int b = blockIdx.x / 10, slice = blockIdx.x % 10;
  const float nw0 = bf2f(vec[VC_NFW + 2 * lane]), nb0 = bf2f(vec[VC_NFB + 2 * lane]);
  const float nw1 = bf2f(vec[VC_NFW + 2 * lane + 1]), nb1 = bf2f(vec[VC_NFB + 2 * lane + 1]);
  float a0 = 0.f, a1 = 0.f;
  for (int t = wv; t < 1200; t += 4) {
    size_t token = (size_t)b * 12000 + slice * 1200 + t;
    unsigned int u = *(const unsigned int*)(X + token * 128 + 2 * lane);
    float x0 = bf2f((u16)(u & 0xffff)), x1 = bf2f((u16)(u >> 16));
    float mean = wsum(x0 + x1) * (1.f / 128.f);
    float var = wsum(x0 * x0 + x1 * x1) * (1.f / 128.f) - mean * mean;
    float rstd = rsqrtf(var + 1e-5f);
    a0 += (x0 - mean) * rstd * nw0 + nb0;
    a1 += (x1 - mean) * rstd * nw1 + nb1;
  }
  sacc[wv][2 * lane] = a0;
  sacc[wv][2 * lane + 1] = a1;
  __syncthreads();
  if (tid < 128) {
    float s = sacc[0][tid] + sacc[1][tid] + sacc[2][tid] + sacc[3][tid];
    atomicAdd(pool + b * 128 + tid, s);
  }
}

// ---------------- head: fp32 output ----------------
__global__ __launch_bounds__(256) void k_head(const float* __restrict__ pool,
                                              const u16* __restrict__ obs,
                                              const u16* __restrict__ vec,
                                              float* __restrict__ out) {
  const int b = blockIdx.x, o = threadIdx.x;
  float acc = bf2f(vec[VC_OBIAS + o]);
  for (int i = 0; i < 128; i++)
    acc += pool[b * 128 + i] * (1.f / 12000.f) * bf2f(vec[VC_OW + i * 256 + o]);
  for (int i = 0; i < 20; i++)
    acc += bf2f(obs[(size_t)b * 132020 + 132000 + i]) * bf2f(vec[VC_OW + (128 + i) * 256 + o]);
  out[b * 256 + o] = acc;
}

extern "C" void kernel_launch(void* const* d_in, const int* in_sizes, int n_in,
                              void* d_out, int out_size, void* d_ws, size_t ws_size,
                              hipStream_t stream) {
  u16* base  = (u16*)d_ws;
  int* flag  = (int*)d_ws;
  float* pool = (float*)((char*)d_ws + 16);
  u16* VEC   = base + 10000;
  u16* WT    = VEC + 45056;
  u16* OBSC  = WT + 393216;
  u16* X     = OBSC + 4224640;   // 49,152,000 — total ~108 MB (no chunk buffers)

  hipMemsetAsync(d_ws, 0, 16 + 32 * 128 * sizeof(float), stream);
  k_scan<<<1, 256, 0, stream>>>((const u16*)d_in[0], flag);
  k_decide<<<1, 64, 0, stream>>>(flag);

  struct CV { int idx; int off; int n; };
  const CV cvs[] = {
      {1, VC_PW, 1408},  {2, VC_PB, 128},   {3, VC_N1W, 256},  {4, VC_N1B, 256},
      {6, VC_QKVB, 768}, {9, VC_PROJB, 256},{10, VC_N2W, 256}, {11, VC_N2B, 256},
      {13, VC_B1, 1024}, {15, VC_B2, 256},  {16, VC_NFW, 128}, {17, VC_NFB, 128},
      {7, VC_RPB, 1458}, {18, VC_OW, 37888},{19, VC_OBIAS, 256}};
  for (const auto& c : cvs)
    k_conv<<<(c.n + 255) / 256, 256, 0, stream>>>(d_in[c.idx], VEC + c.off, c.n, flag);
  k_conv<<<16504, 256, 0, stream>>>(d_in[0], OBSC, 4224640, flag);
  for (int l = 0; l < 2; l++) {
    k_convT2<<<192, 256, 0, stream>>>(d_in[5],  WT + WT_QKV  + l * 49152, 128, 384, l * 49152, flag);
    k_convT2<<<64,  256, 0, stream>>>(d_in[8],  WT + WT_PROJ + l * 16384, 128, 128, l * 16384, flag);
    k_convT2<<<256, 256, 0, stream>>>(d_in[12], WT + WT_W1   + l * 65536, 128, 512, l * 65536, flag);
    k_convT2<<<256, 256, 0, stream>>>(d_in[14], WT + WT_W2   + l * 65536, 512, 128, l * 65536, flag);
  }

  k_patch<<<9600, 256, 0, stream>>>(OBSC, VEC, X);

  for (int l = 0; l < 2; l++) {
    const int shift = l ? 2 : 0;
    k_win<<<3072, 512, 0, stream>>>(X, WT + WT_QKV + l * 49152, WT + WT_PROJ + l * 16384,
                                    VEC + VC_QKVB + l * 384, VEC + VC_PROJB + l * 128,
                                    VEC + VC_N1W + l * 128, VEC + VC_N1B + l * 128,
                                    VEC + VC_RPB + l * 729, shift, l);
    k_mlp<<<1500, 512, 0, stream>>>(X, WT + WT_W1 + l * 65536, VEC + VC_B1 + l * 512,
                                    WT + WT_W2 + l * 65536, VEC + VC_B2 + l * 128,
                                    VEC + VC_N2W + l * 128, VEC + VC_N2B + l * 128);
  }

  k_pool<<<320, 256, 0, stream>>>(X, VEC, pool);
  k_head<<<32, 256, 0, stream>>>(pool, OBSC, VEC, (float*)d_out);
}